// Round 4
// baseline (1377.896 us; speedup 1.0000x reference)
//
#include <hip/hip_runtime.h>
#include <stdint.h>

#define Bb   2
#define Tt   2048
#define Cc_  2048
#define Hh   16
#define Dd   128
#define Mm_  4096            // B*T
#define N1   6144            // 3*C
#define EPSf 1.1920929e-07f
#define SCALE (1.0f/128.0f)  // reference uses 1/D, not 1/sqrt(D)

typedef __bf16 bf16;
typedef __attribute__((ext_vector_type(8))) __bf16 bf16x8;
typedef __attribute__((ext_vector_type(4))) float  f32x4;

// ---- async global->LDS, width 16. LDS dest = wave-uniform base + lane*16.
__device__ __forceinline__ void gl_lds16(const bf16* g, bf16* l) {
  __builtin_amdgcn_global_load_lds(
      (const __attribute__((address_space(1))) unsigned int*)g,
      (__attribute__((address_space(3))) unsigned int*)l, 16, 0, 0);
}

// ------------------------------------------------------------------ cvt x->bf16
__global__ __launch_bounds__(256) void cvt_bf16(const float* __restrict__ in,
                                                bf16* __restrict__ out, int n) {
  int i = (blockIdx.x * 256 + threadIdx.x) * 4;
  if (i >= n) return;
  float4 v = *(const float4*)(in + i);
  union { bf16 h[4]; uint2 u; } o;
  o.h[0] = (bf16)v.x; o.h[1] = (bf16)v.y; o.h[2] = (bf16)v.z; o.h[3] = (bf16)v.w;
  *(uint2*)(out + i) = o.u;
}

// -------------- transpose+convert: [R][Cc]f32 -> [Cc][R]bf16, optional RoPE-pair
// column permutation for the QKV weight (intra-head: new 2d <- d, 2d+1 <- d+64;
// only for cols < 4096 i.e. Q,K sections). Permuting the output ROW index only
// — writes stay contiguous along R.
__global__ __launch_bounds__(256) void transpose_cvt(const float* __restrict__ in,
                                                     bf16* __restrict__ out,
                                                     int R, int Cc, int perm) {
  __shared__ float tile[64][65];
  int c0 = blockIdx.x * 64, r0 = blockIdx.y * 64;
  int tid = threadIdx.x;
#pragma unroll
  for (int j = 0; j < 16; ++j) {
    int idx = tid + j * 256;
    int r = idx >> 6, c = idx & 63;
    tile[r][c] = in[(size_t)(r0 + r) * Cc + c0 + c];
  }
  __syncthreads();
#pragma unroll
  for (int j = 0; j < 16; ++j) {
    int idx = tid + j * 256;
    int rr = idx & 63, cc = idx >> 6;
    int c = c0 + cc;
    int n = c;
    if (perm && c < 4096) {
      int u = c & 127;
      n = (c & ~127) + ((u & 63) << 1) + (u >> 6);
    }
    out[(size_t)n * R + r0 + rr] = (bf16)tile[rr][cc];
  }
}

// ----------------------------------- V transpose: [bh][T][D] -> [bh][D][T] bf16
__global__ __launch_bounds__(256) void vtrans(const bf16* __restrict__ V,
                                              bf16* __restrict__ Vt_) {
  __shared__ bf16 tile[64][72];
  int bh = blockIdx.z, t0 = blockIdx.x * 64, d0 = blockIdx.y * 64;
  int tid = threadIdx.x;
#pragma unroll
  for (int j = 0; j < 2; ++j) {
    int idx = (j * 256 + tid) * 8;
    int r = idx >> 6, c = idx & 63;
    bf16x8 v = *(const bf16x8*)(V + ((size_t)bh * Tt + t0 + r) * Dd + d0 + c);
#pragma unroll
    for (int e = 0; e < 8; ++e) tile[r][c + e] = v[e];
  }
  __syncthreads();
#pragma unroll
  for (int j = 0; j < 2; ++j) {
    int idx = (j * 256 + tid) * 8;
    int dd = idx >> 6, tt = idx & 63;
    bf16x8 v;
#pragma unroll
    for (int e = 0; e < 8; ++e) v[e] = tile[tt + e][dd];
    *(bf16x8*)(Vt_ + ((size_t)bh * Dd + d0 + dd) * Tt + t0 + tt) = v;
  }
}

// ------------------------------------------------------------------ QKV GEMM
// Fused: C = x @ w_qkv (128x128 tile, BK=64) with RMSNorm+RoPE+rearrange in
// the epilogue. N-tile == one head (128 cols, aligned). Q/K cols are in
// RoPE-pair-permuted order (col 2d = orig d, 2d+1 = orig d+64) via wqkvT build.
// Grid: 1536 linear, supercols of 8 n-tiles for B-panel L2 reuse.
__global__ __launch_bounds__(256) void gemm_qkv(const bf16* __restrict__ A,
                                                const bf16* __restrict__ Bt,
                                                const float* __restrict__ qw,
                                                const float* __restrict__ kw,
                                                bf16* __restrict__ Qg,
                                                bf16* __restrict__ Kg,
                                                bf16* __restrict__ Vg) {
  __shared__ __align__(16) bf16 As[128 * 64];
  __shared__ __align__(16) bf16 Bs[128 * 64];
  __shared__ float rs[128][2];
  const int tid = threadIdx.x;
  const int wave = tid >> 6, lane = tid & 63;
  const int quad = lane >> 4, li = lane & 15;
  const int wm = wave >> 1, wn = wave & 1;
  // supercol swizzle: 6 supercols x (8 n-tiles x 32 m-tiles)
  const int bid = blockIdx.x;
  const int sc = bid >> 8, i5 = bid & 255;
  const int n0 = (sc * 8 + (i5 & 7)) * 128;
  const int m0 = (i5 >> 3) * 128;

  f32x4 acc[4][4] = {};

  for (int kt = 0; kt < 2048; kt += 64) {
    __syncthreads();
#pragma unroll
    for (int j = 0; j < 4; ++j) {
      int c = j * 256 + tid;
      int r = c >> 3, cc = c & 7;
      int gc = ((cc ^ (r & 7)) << 3);
      gl_lds16(A + (size_t)(m0 + r) * 2048 + kt + gc, &As[c * 8]);
      gl_lds16(Bt + (size_t)(n0 + r) * 2048 + kt + gc, &Bs[c * 8]);
    }
    __syncthreads();
#pragma unroll
    for (int kc = 0; kc < 2; ++kc) {
      bf16x8 af[4], bfr[4];
#pragma unroll
      for (int t = 0; t < 4; ++t) {
        int rowa = wm * 64 + t * 16 + li;
        af[t] = *(const bf16x8*)&As[rowa * 64 + (((kc * 4 + quad) ^ (rowa & 7)) << 3)];
        int rowb = wn * 64 + t * 16 + li;
        bfr[t] = *(const bf16x8*)&Bs[rowb * 64 + (((kc * 4 + quad) ^ (rowb & 7)) << 3)];
      }
#pragma unroll
      for (int mi = 0; mi < 4; ++mi)
#pragma unroll
        for (int ni = 0; ni < 4; ++ni)
          acc[mi][ni] = __builtin_amdgcn_mfma_f32_16x16x32_bf16(af[mi], bfr[ni],
                                                                acc[mi][ni], 0, 0, 0);
    }
  }

  const int sect = n0 >> 11;       // 0=Q, 1=K, 2=V
  const int h = (n0 >> 7) & 15;

  if (sect < 2) {
    // ---- RMSNorm row sums (sum over this wave's 64 cols, then cross-wn via LDS)
#pragma unroll
    for (int mi = 0; mi < 4; ++mi)
#pragma unroll
      for (int r = 0; r < 4; ++r) {
        float p = 0.f;
#pragma unroll
        for (int ni = 0; ni < 4; ++ni) p += acc[mi][ni][r] * acc[mi][ni][r];
        p += __shfl_xor(p, 1); p += __shfl_xor(p, 2);
        p += __shfl_xor(p, 4); p += __shfl_xor(p, 8);
        if (li == 0) rs[wm * 64 + mi * 16 + quad * 4 + r][wn] = p;
      }
    __syncthreads();
    float rstd[4][4];
#pragma unroll
    for (int mi = 0; mi < 4; ++mi)
#pragma unroll
      for (int r = 0; r < 4; ++r) {
        int row = wm * 64 + mi * 16 + quad * 4 + r;
        rstd[mi][r] = rsqrtf((rs[row][0] + rs[row][1]) * (1.0f / 128.0f) + EPSf);
      }
    const float* nw = (sect == 0) ? qw : kw;
    bf16* Og = (sect == 0) ? Qg : Kg;
#pragma unroll
    for (int ni = 0; ni < 4; ++ni) {
      int j = wn * 64 + ni * 16 + li;                 // permuted col within head
      float invf = exp2f((float)(j >> 1) * (-19.9315685693241740f / 64.0f));
      float w = nw[(j >> 1) + ((j & 1) << 6)];        // weight at ORIG dim
#pragma unroll
      for (int mi = 0; mi < 4; ++mi)
#pragma unroll
        for (int r = 0; r < 4; ++r) {
          int row = wm * 64 + mi * 16 + quad * 4 + r;
          float v = acc[mi][ni][r] * rstd[mi][r] * w;
          float prt = __shfl_xor(v, 1);               // RoPE partner (adjacent li)
          int m = m0 + row, t = m & 2047, b = m >> 11;
          float sn, cs;
          sincosf((float)t * invf, &sn, &cs);
          float ov = (j & 1) ? (v * cs + prt * sn) : (v * cs - prt * sn);
          Og[((size_t)(b * Hh + h) * Tt + t) * Dd + j] = (bf16)ov;
        }
    }
  } else {
    // ---- V: plain rearranged write [bh][t][d] (orig dim order)
#pragma unroll
    for (int ni = 0; ni < 4; ++ni) {
      int j = wn * 64 + ni * 16 + li;
#pragma unroll
      for (int mi = 0; mi < 4; ++mi)
#pragma unroll
        for (int r = 0; r < 4; ++r) {
          int row = wm * 64 + mi * 16 + quad * 4 + r;
          int m = m0 + row, t = m & 2047, b = m >> 11;
          Vg[((size_t)(b * Hh + h) * Tt + t) * Dd + j] = (bf16)acc[mi][ni][r];
        }
    }
  }
}

// ------------------------------------------------------------------ proj GEMM
template <typename OutT>
__global__ __launch_bounds__(256) void gemm_bf16(const bf16* __restrict__ A,
                                                 const bf16* __restrict__ Bt,
                                                 OutT* __restrict__ Cm,
                                                 int Nn, int Kk) {
  __shared__ __align__(16) bf16 As[128 * 64];
  __shared__ __align__(16) bf16 Bs[128 * 64];
  const int tid = threadIdx.x;
  const int wave = tid >> 6, lane = tid & 63;
  const int quad = lane >> 4, li = lane & 15;
  const int wm = wave >> 1, wn = wave & 1;
  const int m0 = blockIdx.y * 128, n0 = blockIdx.x * 128;

  f32x4 acc[4][4] = {};

  for (int kt = 0; kt < Kk; kt += 64) {
    __syncthreads();
#pragma unroll
    for (int j = 0; j < 4; ++j) {
      int c = j * 256 + tid;
      int r = c >> 3, cc = c & 7;
      int gc = ((cc ^ (r & 7)) << 3);
      gl_lds16(A + (size_t)(m0 + r) * Kk + kt + gc, &As[c * 8]);
      gl_lds16(Bt + (size_t)(n0 + r) * Kk + kt + gc, &Bs[c * 8]);
    }
    __syncthreads();
#pragma unroll
    for (int kc = 0; kc < 2; ++kc) {
      bf16x8 af[4], bfr[4];
#pragma unroll
      for (int t = 0; t < 4; ++t) {
        int rowa = wm * 64 + t * 16 + li;
        af[t] = *(const bf16x8*)&As[rowa * 64 + (((kc * 4 + quad) ^ (rowa & 7)) << 3)];
        int rowb = wn * 64 + t * 16 + li;
        bfr[t] = *(const bf16x8*)&Bs[rowb * 64 + (((kc * 4 + quad) ^ (rowb & 7)) << 3)];
      }
#pragma unroll
      for (int mi = 0; mi < 4; ++mi)
#pragma unroll
        for (int ni = 0; ni < 4; ++ni)
          acc[mi][ni] = __builtin_amdgcn_mfma_f32_16x16x32_bf16(af[mi], bfr[ni],
                                                                acc[mi][ni], 0, 0, 0);
    }
  }
#pragma unroll
  for (int mi = 0; mi < 4; ++mi) {
    int row = m0 + wm * 64 + mi * 16 + quad * 4;
#pragma unroll
    for (int ni = 0; ni < 4; ++ni) {
      int col = n0 + wn * 64 + ni * 16 + li;
#pragma unroll
      for (int r = 0; r < 4; ++r)
        Cm[(size_t)(row + r) * Nn + col] = (OutT)acc[mi][ni][r];
    }
  }
}

// ------------------------------------------------------------------ attention
// Single q-tile per block, grid 32bh x 32qt (qt descending), 1024 blocks.
// Exact-bound softmax: q,k RMS-normed (w=1) + RoPE norm-preserving + scale
// 1/128 => |s| <= ~1.01 (Cauchy-Schwarz). No max tracking; L per-lane,
// reduced once at the end.
__global__ __launch_bounds__(256, 3) void attn(const bf16* __restrict__ Qg,
                                               const bf16* __restrict__ Kg,
                                               const bf16* __restrict__ VgT,
                                               bf16* __restrict__ Yg) {
  __shared__ __align__(16) bf16 Kl[64 * 128];
  __shared__ __align__(16) bf16 Vl[128 * 64];
  __shared__ __align__(16) bf16 Pl[4 * 16 * 72];
  const int bh = blockIdx.x;
  const int qt = (int)gridDim.y - 1 - (int)blockIdx.y;  // long blocks first
  const int b = bh >> 4, h = bh & 15;
  const int tid = threadIdx.x, wave = tid >> 6, lane = tid & 63;
  const int quad = lane >> 4, li = lane & 15;
  const int q0 = qt * 64;

  const bf16* Qbase = Qg + ((size_t)bh * Tt + q0 + wave * 16 + li) * Dd;
  bf16x8 qf[4];
#pragma unroll
  for (int kc = 0; kc < 4; ++kc) qf[kc] = *(const bf16x8*)(Qbase + kc * 32 + quad * 8);

  f32x4 o[8] = {};
  float L[4] = {};
  bf16* Pw = &Pl[wave * 16 * 72];

  for (int kt = 0; kt <= qt; ++kt) {
    const int k0 = kt * 64;
    __syncthreads();
#pragma unroll
    for (int j = 0; j < 4; ++j) {
      int c = j * 256 + tid;
      int r = c >> 4, cc = c & 15;
      gl_lds16(Kg + ((size_t)bh * Tt + k0 + r) * Dd + ((cc ^ (r & 7)) << 3), &Kl[c * 8]);
    }
#pragma unroll
    for (int j = 0; j < 4; ++j) {
      int c = j * 256 + tid;
      int r = c >> 3, cc = c & 7;
      gl_lds16(VgT + ((size_t)bh * Dd + r) * Tt + k0 + ((cc ^ (r & 7)) << 3), &Vl[c * 8]);
    }
    __syncthreads();

    f32x4 s4[4] = {};
#pragma unroll
    for (int nt = 0; nt < 4; ++nt) {
      int key = nt * 16 + li;
#pragma unroll
      for (int kc = 0; kc < 4; ++kc) {
        bf16x8 kf = *(const bf16x8*)&Kl[key * 128 + (((kc * 4 + quad) ^ (key & 7)) << 3)];
        s4[nt] = __builtin_amdgcn_mfma_f32_16x16x32_bf16(qf[kc], kf, s4[nt], 0, 0, 0);
      }
    }
    const bool diag = (kt == qt);
#pragma unroll
    for (int nt = 0; nt < 4; ++nt)
#pragma unroll
      for (int r = 0; r < 4; ++r) {
        float e = __expf(s4[nt][r] * SCALE);
        if (diag && (nt * 16 + li > wave * 16 + quad * 4 + r)) e = 0.f;
        L[r] += e;
        Pw[(quad * 4 + r) * 72 + nt * 16 + li] = (bf16)e;
      }
#pragma unroll
    for (int kc = 0; kc < 2; ++kc) {
      bf16x8 pf = *(const bf16x8*)&Pw[li * 72 + kc * 32 + quad * 8];
#pragma unroll
      for (int u = 0; u < 8; ++u) {
        bf16x8 vf = *(const bf16x8*)&Vl[(u * 16 + li) * 64 + (((kc * 4 + quad) ^ (li & 7)) << 3)];
        o[u] = __builtin_amdgcn_mfma_f32_16x16x32_bf16(pf, vf, o[u], 0, 0, 0);
      }
    }
  }

  float inv[4];
#pragma unroll
  for (int r = 0; r < 4; ++r) {
    float s0 = L[r];
#pragma unroll
    for (int off = 1; off < 16; off <<= 1) s0 += __shfl_xor(s0, off);
    inv[r] = 1.0f / s0;
  }
  int trow = q0 + wave * 16 + quad * 4;
#pragma unroll
  for (int u = 0; u < 8; ++u) {
    int col = h * Dd + u * 16 + li;
#pragma unroll
    for (int r = 0; r < 4; ++r)
      Yg[(size_t)(b * Tt + trow + r) * Cc_ + col] = (bf16)(o[u][r] * inv[r]);
  }
}

// ------------------------------------------------------------------ launch
extern "C" void kernel_launch(void* const* d_in, const int* in_sizes, int n_in,
                              void* d_out, int out_size, void* d_ws, size_t ws_size,
                              hipStream_t stream) {
  const float* x      = (const float*)d_in[0];
  const float* w_qkv  = (const float*)d_in[1];
  const float* w_proj = (const float*)d_in[2];
  const float* qnw    = (const float*)d_in[3];
  const float* knw    = (const float*)d_in[4];
  float* out = (float*)d_out;

  // workspace partition (bf16 elements)
  bf16* xb     = (bf16*)d_ws;                       // dead after QKV GEMM
  bf16* wqkvT  = xb + (size_t)Mm_ * Cc_;
  bf16* wprojT = wqkvT + (size_t)N1 * Cc_;
  bf16* Qg     = wprojT + (size_t)Cc_ * Cc_;
  bf16* Kg     = Qg + (size_t)Bb * Hh * Tt * Dd;
  bf16* Vg     = Kg + (size_t)Bb * Hh * Tt * Dd;
  bf16* Yg     = Vg + (size_t)Bb * Hh * Tt * Dd;
  bf16* VgT    = xb;   // alias: exactly xb's size, alive after QKV GEMM done

  hipLaunchKernelGGL(cvt_bf16, dim3((Mm_ * Cc_ / 4) / 256), dim3(256), 0, stream,
                     x, xb, Mm_ * Cc_);
  hipLaunchKernelGGL(transpose_cvt, dim3(N1 / 64, Cc_ / 64), dim3(256), 0, stream,
                     w_qkv, wqkvT, Cc_, N1, 1);
  hipLaunchKernelGGL(transpose_cvt, dim3(Cc_ / 64, Cc_ / 64), dim3(256), 0, stream,
                     w_proj, wprojT, Cc_, Cc_, 0);
  hipLaunchKernelGGL(gemm_qkv, dim3((N1 / 128) * (Mm_ / 128)), dim3(256), 0, stream,
                     xb, wqkvT, qnw, knw, Qg, Kg, Vg);
  hipLaunchKernelGGL(vtrans, dim3(Tt / 64, Dd / 64, Bb * Hh), dim3(256), 0, stream,
                     Vg, VgT);
  hipLaunchKernelGGL(attn, dim3(Bb * Hh, Tt / 64), dim3(256), 0, stream,
                     Qg, Kg, VgT, Yg);
  hipLaunchKernelGGL(gemm_bf16<float>, dim3(Cc_ / 128, Mm_ / 128), dim3(256), 0, stream,
                     Yg, wprojT, out, Cc_, Cc_);
}

// Round 5
// 392.641 us; speedup vs baseline: 3.5093x; 3.5093x over previous
//
#include <hip/hip_runtime.h>
#include <stdint.h>

#define Bb   2
#define Tt   2048
#define Cc_  2048
#define Hh   16
#define Dd   128
#define Mm_  4096            // B*T
#define N1   6144            // 3*C
#define EPSf 1.1920929e-07f
#define SCALE (1.0f/128.0f)  // reference uses 1/D, not 1/sqrt(D)

typedef __bf16 bf16;
typedef __attribute__((ext_vector_type(8))) __bf16 bf16x8;
typedef __attribute__((ext_vector_type(4))) float  f32x4;

// ---- async global->LDS, width 16. LDS dest = wave-uniform base + lane*16.
__device__ __forceinline__ void gl_lds16(const bf16* g, bf16* l) {
  __builtin_amdgcn_global_load_lds(
      (const __attribute__((address_space(1))) unsigned int*)g,
      (__attribute__((address_space(3))) unsigned int*)l, 16, 0, 0);
}

// ------------------------------------------------------------------ cvt x->bf16
__global__ __launch_bounds__(256) void cvt_bf16(const float* __restrict__ in,
                                                bf16* __restrict__ out, int n) {
  int i = (blockIdx.x * 256 + threadIdx.x) * 4;
  if (i >= n) return;
  float4 v = *(const float4*)(in + i);
  union { bf16 h[4]; uint2 u; } o;
  o.h[0] = (bf16)v.x; o.h[1] = (bf16)v.y; o.h[2] = (bf16)v.z; o.h[3] = (bf16)v.w;
  *(uint2*)(out + i) = o.u;
}

// -------------- transpose+convert: [R][Cc]f32 -> [Cc][R]bf16, optional RoPE-pair
// column permutation for the QKV weight (intra-head: new 2d <- d, 2d+1 <- d+64;
// only for cols < 4096 i.e. Q,K sections).
__global__ __launch_bounds__(256) void transpose_cvt(const float* __restrict__ in,
                                                     bf16* __restrict__ out,
                                                     int R, int Cc, int perm) {
  __shared__ float tile[64][65];
  int c0 = blockIdx.x * 64, r0 = blockIdx.y * 64;
  int tid = threadIdx.x;
#pragma unroll
  for (int j = 0; j < 16; ++j) {
    int idx = tid + j * 256;
    int r = idx >> 6, c = idx & 63;
    tile[r][c] = in[(size_t)(r0 + r) * Cc + c0 + c];
  }
  __syncthreads();
#pragma unroll
  for (int j = 0; j < 16; ++j) {
    int idx = tid + j * 256;
    int rr = idx & 63, cc = idx >> 6;
    int c = c0 + cc;
    int n = c;
    if (perm && c < 4096) {
      int u = c & 127;
      n = (c & ~127) + ((u & 63) << 1) + (u >> 6);
    }
    out[(size_t)n * R + r0 + rr] = (bf16)tile[rr][cc];
  }
}

// ----------------------------------- V transpose: [bh][T][D] -> [bh][D][T] bf16
__global__ __launch_bounds__(256) void vtrans(const bf16* __restrict__ V,
                                              bf16* __restrict__ Vt_) {
  __shared__ bf16 tile[64][72];
  int bh = blockIdx.z, t0 = blockIdx.x * 64, d0 = blockIdx.y * 64;
  int tid = threadIdx.x;
#pragma unroll
  for (int j = 0; j < 2; ++j) {
    int idx = (j * 256 + tid) * 8;
    int r = idx >> 6, c = idx & 63;
    bf16x8 v = *(const bf16x8*)(V + ((size_t)bh * Tt + t0 + r) * Dd + d0 + c);
#pragma unroll
    for (int e = 0; e < 8; ++e) tile[r][c + e] = v[e];
  }
  __syncthreads();
#pragma unroll
  for (int j = 0; j < 2; ++j) {
    int idx = (j * 256 + tid) * 8;
    int dd = idx >> 6, tt = idx & 63;
    bf16x8 v;
#pragma unroll
    for (int e = 0; e < 8; ++e) v[e] = tile[tt + e][dd];
    *(bf16x8*)(Vt_ + ((size_t)bh * Dd + d0 + dd) * Tt + t0 + tt) = v;
  }
}

// ------------------------------------------------------------------ QKV GEMM
// Fused: C = x @ w_qkv (128x128 tile, BK=64) with RMSNorm+RoPE+rearrange in
// the epilogue. N-tile == one head. Q/K cols RoPE-pair-permuted (col 2d = orig
// d, 2d+1 = orig d+64) via wqkvT build. Trig via manual range reduction +
// __sinf/__cosf (pure VALU, v_sin_f32/v_cos_f32 — NO sincosf: its pointer
// out-params forced 4.4 GB of scratch traffic in round 4).
__global__ __launch_bounds__(256) void gemm_qkv(const bf16* __restrict__ A,
                                                const bf16* __restrict__ Bt,
                                                const float* __restrict__ qw,
                                                const float* __restrict__ kw,
                                                bf16* __restrict__ Qg,
                                                bf16* __restrict__ Kg,
                                                bf16* __restrict__ Vg) {
  __shared__ __align__(16) bf16 As[128 * 64];
  __shared__ __align__(16) bf16 Bs[128 * 64];
  __shared__ float rs[128][2];
  const int tid = threadIdx.x;
  const int wave = tid >> 6, lane = tid & 63;
  const int quad = lane >> 4, li = lane & 15;
  const int wm = wave >> 1, wn = wave & 1;
  const int n0 = blockIdx.x * 128, m0 = blockIdx.y * 128;

  f32x4 acc[4][4] = {};

  for (int kt = 0; kt < 2048; kt += 64) {
    __syncthreads();
#pragma unroll
    for (int j = 0; j < 4; ++j) {
      int c = j * 256 + tid;
      int r = c >> 3, cc = c & 7;
      int gc = ((cc ^ (r & 7)) << 3);
      gl_lds16(A + (size_t)(m0 + r) * 2048 + kt + gc, &As[c * 8]);
      gl_lds16(Bt + (size_t)(n0 + r) * 2048 + kt + gc, &Bs[c * 8]);
    }
    __syncthreads();
#pragma unroll
    for (int kc = 0; kc < 2; ++kc) {
      bf16x8 af[4], bfr[4];
#pragma unroll
      for (int t = 0; t < 4; ++t) {
        int rowa = wm * 64 + t * 16 + li;
        af[t] = *(const bf16x8*)&As[rowa * 64 + (((kc * 4 + quad) ^ (rowa & 7)) << 3)];
        int rowb = wn * 64 + t * 16 + li;
        bfr[t] = *(const bf16x8*)&Bs[rowb * 64 + (((kc * 4 + quad) ^ (rowb & 7)) << 3)];
      }
#pragma unroll
      for (int mi = 0; mi < 4; ++mi)
#pragma unroll
        for (int ni = 0; ni < 4; ++ni)
          acc[mi][ni] = __builtin_amdgcn_mfma_f32_16x16x32_bf16(af[mi], bfr[ni],
                                                                acc[mi][ni], 0, 0, 0);
    }
  }

  const int sect = n0 >> 11;       // 0=Q, 1=K, 2=V
  const int h = (n0 >> 7) & 15;

  if (sect < 2) {
    // ---- RMSNorm row sums (sum over this wave's 64 cols, then cross-wn via LDS)
#pragma unroll
    for (int mi = 0; mi < 4; ++mi)
#pragma unroll
      for (int r = 0; r < 4; ++r) {
        float p = 0.f;
#pragma unroll
        for (int ni = 0; ni < 4; ++ni) p += acc[mi][ni][r] * acc[mi][ni][r];
        p += __shfl_xor(p, 1); p += __shfl_xor(p, 2);
        p += __shfl_xor(p, 4); p += __shfl_xor(p, 8);
        if (li == 0) rs[wm * 64 + mi * 16 + quad * 4 + r][wn] = p;
      }
    __syncthreads();
    float rstd[4][4];
#pragma unroll
    for (int mi = 0; mi < 4; ++mi)
#pragma unroll
      for (int r = 0; r < 4; ++r) {
        int row = wm * 64 + mi * 16 + quad * 4 + r;
        rstd[mi][r] = rsqrtf((rs[row][0] + rs[row][1]) * (1.0f / 128.0f) + EPSf);
      }
    const float* nw = (sect == 0) ? qw : kw;
    bf16* Og = (sect == 0) ? Qg : Kg;
#pragma unroll
    for (int ni = 0; ni < 4; ++ni) {
      int j = wn * 64 + ni * 16 + li;                 // permuted col within head
      // inv_freq in REVOLUTIONS: 1e6^(-(j>>1)/64) / 2pi
      float invf_rev = exp2f((float)(j >> 1) * (-19.9315685693241740f / 64.0f))
                       * 0.15915494309189535f;
      float w = nw[(j >> 1) + ((j & 1) << 6)];        // weight at ORIG dim
#pragma unroll
      for (int mi = 0; mi < 4; ++mi)
#pragma unroll
        for (int r = 0; r < 4; ++r) {
          int row = wm * 64 + mi * 16 + quad * 4 + r;
          float v = acc[mi][ni][r] * rstd[mi][r] * w;
          float prt = __shfl_xor(v, 1);               // RoPE partner (adjacent li)
          int m = m0 + row, t = m & 2047, b = m >> 11;
          float rev = (float)t * invf_rev;
          rev -= floorf(rev);                         // range-reduce to [0,1)
          float ang = rev * 6.28318530717958647f;
          float sn = __sinf(ang), cs = __cosf(ang);   // v_sin/v_cos, no scratch
          float ov = (j & 1) ? (v * cs + prt * sn) : (v * cs - prt * sn);
          Og[((size_t)(b * Hh + h) * Tt + t) * Dd + j] = (bf16)ov;
        }
    }
  } else {
    // ---- V: plain rearranged write [bh][t][d] (orig dim order)
#pragma unroll
    for (int ni = 0; ni < 4; ++ni) {
      int j = wn * 64 + ni * 16 + li;
#pragma unroll
      for (int mi = 0; mi < 4; ++mi)
#pragma unroll
        for (int r = 0; r < 4; ++r) {
          int row = wm * 64 + mi * 16 + quad * 4 + r;
          int m = m0 + row, t = m & 2047, b = m >> 11;
          Vg[((size_t)(b * Hh + h) * Tt + t) * Dd + j] = (bf16)acc[mi][ni][r];
        }
    }
  }
}

// ------------------------------------------------------------------ proj GEMM
template <typename OutT>
__global__ __launch_bounds__(256) void gemm_bf16(const bf16* __restrict__ A,
                                                 const bf16* __restrict__ Bt,
                                                 OutT* __restrict__ Cm,
                                                 int Nn, int Kk) {
  __shared__ __align__(16) bf16 As[128 * 64];
  __shared__ __align__(16) bf16 Bs[128 * 64];
  const int tid = threadIdx.x;
  const int wave = tid >> 6, lane = tid & 63;
  const int quad = lane >> 4, li = lane & 15;
  const int wm = wave >> 1, wn = wave & 1;
  const int m0 = blockIdx.y * 128, n0 = blockIdx.x * 128;

  f32x4 acc[4][4] = {};

  for (int kt = 0; kt < Kk; kt += 64) {
    __syncthreads();
#pragma unroll
    for (int j = 0; j < 4; ++j) {
      int c = j * 256 + tid;
      int r = c >> 3, cc = c & 7;
      int gc = ((cc ^ (r & 7)) << 3);
      gl_lds16(A + (size_t)(m0 + r) * Kk + kt + gc, &As[c * 8]);
      gl_lds16(Bt + (size_t)(n0 + r) * Kk + kt + gc, &Bs[c * 8]);
    }
    __syncthreads();
#pragma unroll
    for (int kc = 0; kc < 2; ++kc) {
      bf16x8 af[4], bfr[4];
#pragma unroll
      for (int t = 0; t < 4; ++t) {
        int rowa = wm * 64 + t * 16 + li;
        af[t] = *(const bf16x8*)&As[rowa * 64 + (((kc * 4 + quad) ^ (rowa & 7)) << 3)];
        int rowb = wn * 64 + t * 16 + li;
        bfr[t] = *(const bf16x8*)&Bs[rowb * 64 + (((kc * 4 + quad) ^ (rowb & 7)) << 3)];
      }
#pragma unroll
      for (int mi = 0; mi < 4; ++mi)
#pragma unroll
        for (int ni = 0; ni < 4; ++ni)
          acc[mi][ni] = __builtin_amdgcn_mfma_f32_16x16x32_bf16(af[mi], bfr[ni],
                                                                acc[mi][ni], 0, 0, 0);
    }
  }
#pragma unroll
  for (int mi = 0; mi < 4; ++mi) {
    int row = m0 + wm * 64 + mi * 16 + quad * 4;
#pragma unroll
    for (int ni = 0; ni < 4; ++ni) {
      int col = n0 + wn * 64 + ni * 16 + li;
#pragma unroll
      for (int r = 0; r < 4; ++r)
        Cm[(size_t)(row + r) * Nn + col] = (OutT)acc[mi][ni][r];
    }
  }
}

// ------------------------------------------------------------------ attention
// Single q-tile per block, grid 32bh x 32qt (qt descending), 1024 blocks.
// Exact-bound softmax: |s| <= ~1.01 (RMS-normed q,k + 1/128 scale), so no max
// tracking; L per-lane, reduced once at the end.
__global__ __launch_bounds__(256, 3) void attn(const bf16* __restrict__ Qg,
                                               const bf16* __restrict__ Kg,
                                               const bf16* __restrict__ VgT,
                                               bf16* __restrict__ Yg) {
  __shared__ __align__(16) bf16 Kl[64 * 128];
  __shared__ __align__(16) bf16 Vl[128 * 64];
  __shared__ __align__(16) bf16 Pl[4 * 16 * 72];
  const int bh = blockIdx.x;
  const int qt = (int)gridDim.y - 1 - (int)blockIdx.y;  // long blocks first
  const int b = bh >> 4, h = bh & 15;
  const int tid = threadIdx.x, wave = tid >> 6, lane = tid & 63;
  const int quad = lane >> 4, li = lane & 15;
  const int q0 = qt * 64;

  const bf16* Qbase = Qg + ((size_t)bh * Tt + q0 + wave * 16 + li) * Dd;
  bf16x8 qf[4];
#pragma unroll
  for (int kc = 0; kc < 4; ++kc) qf[kc] = *(const bf16x8*)(Qbase + kc * 32 + quad * 8);

  f32x4 o[8] = {};
  float L[4] = {};
  bf16* Pw = &Pl[wave * 16 * 72];

  for (int kt = 0; kt <= qt; ++kt) {
    const int k0 = kt * 64;
    __syncthreads();
#pragma unroll
    for (int j = 0; j < 4; ++j) {
      int c = j * 256 + tid;
      int r = c >> 4, cc = c & 15;
      gl_lds16(Kg + ((size_t)bh * Tt + k0 + r) * Dd + ((cc ^ (r & 7)) << 3), &Kl[c * 8]);
    }
#pragma unroll
    for (int j = 0; j < 4; ++j) {
      int c = j * 256 + tid;
      int r = c >> 3, cc = c & 7;
      gl_lds16(VgT + ((size_t)bh * Dd + r) * Tt + k0 + ((cc ^ (r & 7)) << 3), &Vl[c * 8]);
    }
    __syncthreads();

    f32x4 s4[4] = {};
#pragma unroll
    for (int nt = 0; nt < 4; ++nt) {
      int key = nt * 16 + li;
#pragma unroll
      for (int kc = 0; kc < 4; ++kc) {
        bf16x8 kf = *(const bf16x8*)&Kl[key * 128 + (((kc * 4 + quad) ^ (key & 7)) << 3)];
        s4[nt] = __builtin_amdgcn_mfma_f32_16x16x32_bf16(qf[kc], kf, s4[nt], 0, 0, 0);
      }
    }
    const bool diag = (kt == qt);
#pragma unroll
    for (int nt = 0; nt < 4; ++nt)
#pragma unroll
      for (int r = 0; r < 4; ++r) {
        float e = __expf(s4[nt][r] * SCALE);
        if (diag && (nt * 16 + li > wave * 16 + quad * 4 + r)) e = 0.f;
        L[r] += e;
        Pw[(quad * 4 + r) * 72 + nt * 16 + li] = (bf16)e;
      }
#pragma unroll
    for (int kc = 0; kc < 2; ++kc) {
      bf16x8 pf = *(const bf16x8*)&Pw[li * 72 + kc * 32 + quad * 8];
#pragma unroll
      for (int u = 0; u < 8; ++u) {
        bf16x8 vf = *(const bf16x8*)&Vl[(u * 16 + li) * 64 + (((kc * 4 + quad) ^ (li & 7)) << 3)];
        o[u] = __builtin_amdgcn_mfma_f32_16x16x32_bf16(pf, vf, o[u], 0, 0, 0);
      }
    }
  }

  float inv[4];
#pragma unroll
  for (int r = 0; r < 4; ++r) {
    float s0 = L[r];
#pragma unroll
    for (int off = 1; off < 16; off <<= 1) s0 += __shfl_xor(s0, off);
    inv[r] = 1.0f / s0;
  }
  int trow = q0 + wave * 16 + quad * 4;
#pragma unroll
  for (int u = 0; u < 8; ++u) {
    int col = h * Dd + u * 16 + li;
#pragma unroll
    for (int r = 0; r < 4; ++r)
      Yg[(size_t)(b * Tt + trow + r) * Cc_ + col] = (bf16)(o[u][r] * inv[r]);
  }
}

// ------------------------------------------------------------------ launch
extern "C" void kernel_launch(void* const* d_in, const int* in_sizes, int n_in,
                              void* d_out, int out_size, void* d_ws, size_t ws_size,
                              hipStream_t stream) {
  const float* x      = (const float*)d_in[0];
  const float* w_qkv  = (const float*)d_in[1];
  const float* w_proj = (const float*)d_in[2];
  const float* qnw    = (const float*)d_in[3];
  const float* knw    = (const float*)d_in[4];
  float* out = (float*)d_out;

  // workspace partition (bf16 elements)
  bf16* xb     = (bf16*)d_ws;                       // dead after QKV GEMM
  bf16* wqkvT  = xb + (size_t)Mm_ * Cc_;
  bf16* wprojT = wqkvT + (size_t)N1 * Cc_;
  bf16* Qg     = wprojT + (size_t)Cc_ * Cc_;
  bf16* Kg     = Qg + (size_t)Bb * Hh * Tt * Dd;
  bf16* Vg     = Kg + (size_t)Bb * Hh * Tt * Dd;
  bf16* Yg     = Vg + (size_t)Bb * Hh * Tt * Dd;
  bf16* VgT    = xb;   // alias: exactly xb's size, alive after QKV GEMM done

  hipLaunchKernelGGL(cvt_bf16, dim3((Mm_ * Cc_ / 4) / 256), dim3(256), 0, stream,
                     x, xb, Mm_ * Cc_);
  hipLaunchKernelGGL(transpose_cvt, dim3(N1 / 64, Cc_ / 64), dim3(256), 0, stream,
                     w_qkv, wqkvT, Cc_, N1, 1);
  hipLaunchKernelGGL(transpose_cvt, dim3(Cc_ / 64, Cc_ / 64), dim3(256), 0, stream,
                     w_proj, wprojT, Cc_, Cc_, 0);
  hipLaunchKernelGGL(gemm_qkv, dim3(N1 / 128, Mm_ / 128), dim3(256), 0, stream,
                     xb, wqkvT, qnw, knw, Qg, Kg, Vg);
  hipLaunchKernelGGL(vtrans, dim3(Tt / 64, Dd / 64, Bb * Hh), dim3(256), 0, stream,
                     Vg, VgT);
  hipLaunchKernelGGL(attn, dim3(Bb * Hh, Tt / 64), dim3(256), 0, stream,
                     Qg, Kg, VgT, Yg);
  hipLaunchKernelGGL(gemm_bf16<float>, dim3(Cc_ / 128, Mm_ / 128), dim3(256), 0, stream,
                     Yg, wprojT, out, Cc_, Cc_);
}